// Round 10
// baseline (303.442 us; speedup 1.0000x reference)
//
#include <hip/hip_runtime.h>
#include <hip/hip_fp16.h>
#include <math.h>

#define N_NODES 50000
#define N_EDGES 20000
#define NNZ_C   1000000
#define F_IN    128
#define HID     64
#define NCLS    40
#define NLAYER  4
#define ALPHA   0.1f

#define ESHIFT  6                        // 64 edges / bucket
#define VSHIFT  7                        // 128 vertices / bucket
#define NB_E    ((N_EDGES + 63) / 64)    // 313
#define NB_V    ((N_NODES + 127) / 128)  // 391
#define NB_TOT  (NB_E + NB_V)            // 704

typedef _Float16 f16x8 __attribute__((ext_vector_type(8)));
typedef float    f32x4 __attribute__((ext_vector_type(4)));

// ---------------- X0h = relu(x @ W0 + b0) via MFMA, fp16 out ----------------
__global__ __launch_bounds__(256) void input_gemm(
    const float* __restrict__ x, const float* __restrict__ W0,
    const float* __restrict__ b0, _Float16* __restrict__ X0h)
{
    int lane = threadIdx.x & 63;
    int wv   = threadIdx.x >> 6;
    int r16  = lane & 15;
    int kgrp = lane >> 4;                    // 0..3
    f16x8 bf[4][4];
    #pragma unroll
    for (int n0 = 0; n0 < 4; ++n0)
        #pragma unroll
        for (int kh = 0; kh < 4; ++kh)
            #pragma unroll
            for (int j = 0; j < 8; ++j)
                bf[n0][kh][j] = (_Float16)W0[(kh * 32 + kgrp * 8 + j) * HID + n0 * 16 + r16];
    float bias[4];
    #pragma unroll
    for (int n0 = 0; n0 < 4; ++n0) bias[n0] = b0[n0 * 16 + r16];

    int nwaves = gridDim.x * 4;
    for (int t = blockIdx.x * 4 + wv; t < N_NODES / 16; t += nwaves) {
        int row0 = t * 16;
        const float* xp = x + (size_t)(row0 + r16) * F_IN + kgrp * 8;
        f16x8 a[4];
        #pragma unroll
        for (int kh = 0; kh < 4; ++kh) {
            float4 u0 = *(const float4*)(xp + kh * 32);
            float4 u1 = *(const float4*)(xp + kh * 32 + 4);
            a[kh][0] = (_Float16)u0.x; a[kh][1] = (_Float16)u0.y;
            a[kh][2] = (_Float16)u0.z; a[kh][3] = (_Float16)u0.w;
            a[kh][4] = (_Float16)u1.x; a[kh][5] = (_Float16)u1.y;
            a[kh][6] = (_Float16)u1.z; a[kh][7] = (_Float16)u1.w;
        }
        #pragma unroll
        for (int n0 = 0; n0 < 4; ++n0) {
            f32x4 acc = {0.f, 0.f, 0.f, 0.f};
            #pragma unroll
            for (int kh = 0; kh < 4; ++kh)
                acc = __builtin_amdgcn_mfma_f32_16x16x32_f16(a[kh], bf[n0][kh], acc, 0, 0, 0);
            #pragma unroll
            for (int r = 0; r < 4; ++r) {
                float y = acc[r] + bias[n0];
                y = y > 0.f ? y : 0.f;
                X0h[(size_t)(row0 + kgrp * 4 + r) * HID + n0 * 16 + r16] = (_Float16)y;
            }
        }
    }
}

// ---------------- W'[l] = (1-beta_l) I + beta_l Ws[l], fp16 ----------------
__global__ __launch_bounds__(256) void make_wp(
    const float* __restrict__ Ws, _Float16* __restrict__ Wp,
    float be0, float be1, float be2, float be3)
{
    int l = blockIdx.x;
    float beta = (l == 0) ? be0 : (l == 1) ? be1 : (l == 2) ? be2 : be3;
    for (int i = threadIdx.x; i < HID * HID; i += 256) {
        int k = i >> 6, n = i & 63;
        float v = beta * Ws[l * HID * HID + i] + ((k == n) ? (1.f - beta) : 0.f);
        Wp[l * HID * HID + i] = (_Float16)v;
    }
}

// ---------------- per-block LDS bucket histogram (704 coarse buckets) ----------------
__global__ __launch_bounds__(256) void bucket_hist(
    const int* __restrict__ vertex, const int* __restrict__ edges,
    int* __restrict__ gcnt)
{
    __shared__ int h[NB_TOT];
    int tid = threadIdx.x;
    for (int i = tid; i < NB_TOT; i += 256) h[i] = 0;
    __syncthreads();
    int base = blockIdx.x * 4096;
    int n = NNZ_C - base; if (n > 4096) n = 4096;   // always multiple of 4
    for (int i = tid * 4; i < n; i += 1024) {
        int4 e4 = *(const int4*)(edges  + base + i);
        int4 v4 = *(const int4*)(vertex + base + i);
        atomicAdd(&h[e4.x >> ESHIFT], 1);
        atomicAdd(&h[e4.y >> ESHIFT], 1);
        atomicAdd(&h[e4.z >> ESHIFT], 1);
        atomicAdd(&h[e4.w >> ESHIFT], 1);
        atomicAdd(&h[NB_E + (v4.x >> VSHIFT)], 1);
        atomicAdd(&h[NB_E + (v4.y >> VSHIFT)], 1);
        atomicAdd(&h[NB_E + (v4.z >> VSHIFT)], 1);
        atomicAdd(&h[NB_E + (v4.w >> VSHIFT)], 1);
    }
    __syncthreads();
    for (int i = tid; i < NB_TOT; i += 256)
        if (h[i]) atomicAdd(&gcnt[i], h[i]);
}

// ---------------- scan 704 bucket counts -> bucket offsets + cursors ----------------
__global__ __launch_bounds__(1024) void bucket_scan(
    const int* __restrict__ gcnt, int* __restrict__ boff_e,
    int* __restrict__ boff_v, int* __restrict__ curb)
{
    __shared__ int tmp[1024];
    int tid = threadIdx.x;
    int v = (tid < NB_TOT) ? gcnt[tid] : 0;
    tmp[tid] = v;
    __syncthreads();
    for (int d = 1; d < 1024; d <<= 1) {
        int t = (tid >= d) ? tmp[tid - d] : 0;
        __syncthreads();
        tmp[tid] += t;
        __syncthreads();
    }
    if (tid < NB_TOT) {
        int excl = tmp[tid] - v;
        int off = (tid < NB_E) ? excl : excl - NNZ_C;  // v-part 0-based
        if (tid < NB_E) boff_e[tid] = off; else boff_v[tid - NB_E] = off;
        curb[tid] = off;
    }
    if (tid == 0) { boff_e[NB_E] = NNZ_C; boff_v[NB_V] = NNZ_C; }
}

// ---------------- pass 1 (both sides): bin packed 32-bit pairs ----------------
__global__ __launch_bounds__(256) void bin_pass1_both(
    const int* __restrict__ vertex, const int* __restrict__ edges,
    int* __restrict__ curb,
    unsigned* __restrict__ binned_e,
    unsigned* __restrict__ binned_v)
{
    __shared__ int hist[NB_TOT];
    __shared__ int base[NB_TOT];
    int tid = threadIdx.x;
    int blk = blockIdx.x * 4096;
    int nh = NNZ_C - blk; if (nh > 4096) nh = 4096;
    for (int i = tid; i < NB_TOT; i += 256) hist[i] = 0;
    __syncthreads();
    for (int i = tid; i < nh; i += 256) {
        atomicAdd(&hist[edges[blk + i] >> ESHIFT], 1);
        atomicAdd(&hist[NB_E + (vertex[blk + i] >> VSHIFT)], 1);
    }
    __syncthreads();
    for (int i = tid; i < NB_TOT; i += 256) {
        int c = hist[i];
        base[i] = c ? atomicAdd(&curb[i], c) : 0;
        hist[i] = 0;
    }
    __syncthreads();
    for (int i = tid; i < nh; i += 256) {
        int e = edges[blk + i], v = vertex[blk + i];
        int be = e >> ESHIFT;
        int r  = atomicAdd(&hist[be], 1);
        binned_e[base[be] + r] = ((unsigned)e << 16) | (unsigned)v;   // e<2^15, v<2^16
        int bv = NB_E + (v >> VSHIFT);
        int r2 = atomicAdd(&hist[bv], 1);
        binned_v[base[bv] + r2] = ((unsigned)v << 15) | (unsigned)e;  // v<2^17, e<2^15
    }
}

// ---------------- pass 2: per bucket -> local count/scan, write off/inv, place adj ----------------
__global__ __launch_bounds__(256) void bin_pass2f(
    const unsigned* __restrict__ binned, const int* __restrict__ boff,
    int shift, int kshift, int nkeys,
    int* __restrict__ off, float* __restrict__ inv, int* __restrict__ adj)
{
    __shared__ int lcnt[128];
    __shared__ int ts[128];
    __shared__ int lcur[128];
    int b  = blockIdx.x;
    int k0 = b << shift;
    int bs = 1 << shift;
    int kn = nkeys - k0; if (kn > bs) kn = bs;
    int tid = threadIdx.x;
    unsigned vmask = (1u << kshift) - 1u;
    if (tid < 128) lcnt[tid] = 0;
    __syncthreads();
    int beg = boff[b], end = boff[b + 1];
    for (int j = beg + tid; j < end; j += 256)
        atomicAdd(&lcnt[(int)(binned[j] >> kshift) - k0], 1);
    __syncthreads();
    int c = 0;
    if (tid < 128) { c = lcnt[tid]; ts[tid] = c; }
    __syncthreads();
    #pragma unroll
    for (int d = 1; d < 128; d <<= 1) {
        int t = 0;
        if (tid < 128 && tid >= d) t = ts[tid - d];
        __syncthreads();
        if (tid < 128) ts[tid] += t;
        __syncthreads();
    }
    if (tid < kn) {
        int pos = beg + ts[tid] - c;
        off[k0 + tid] = pos;
        inv[k0 + tid] = 1.0f / fmaxf((float)c, 1.0f);
        lcur[tid] = pos;
    }
    if (b == 0 && tid == 0) off[nkeys] = NNZ_C;
    __syncthreads();
    for (int j = beg + tid; j < end; j += 256) {
        unsigned p = binned[j];
        int k = (int)(p >> kshift) - k0;
        int v = (int)(p & vmask);
        adj[atomicAdd(&lcur[k], 1)] = v;
    }
}

// ---- chunk core: 8 groups x 8 rows from one 64-index vector ----------------
__device__ __forceinline__ void process_chunk(
    const __half* __restrict__ src, int myidx, int nj, int lane, float acc[8])
{
    int g = lane >> 3, c = lane & 7;
    int idx[8];
    #pragma unroll
    for (int s = 0; s < 8; ++s)
        idx[s] = __shfl(myidx, ((s << 3) + g) & 63);
    #pragma unroll
    for (int s = 0; s < 8; ++s) {
        int r = (s << 3) + g;
        if (r < nj) {
            uint4 raw = ((const uint4*)(src + (size_t)idx[s] * HID))[c];
            union { uint4 u; __half2 h[4]; } U; U.u = raw;
            float2 f0 = __half22float2(U.h[0]);
            float2 f1 = __half22float2(U.h[1]);
            float2 f2 = __half22float2(U.h[2]);
            float2 f3 = __half22float2(U.h[3]);
            acc[0] += f0.x; acc[1] += f0.y;
            acc[2] += f1.x; acc[3] += f1.y;
            acc[4] += f2.x; acc[5] += f2.y;
            acc[6] += f3.x; acc[7] += f3.y;
        }
    }
}

__device__ __forceinline__ void reduce_groups(float acc[8])
{
    #pragma unroll
    for (int q = 0; q < 8; ++q) {
        acc[q] += __shfl_xor(acc[q], 8);
        acc[q] += __shfl_xor(acc[q], 16);
        acc[q] += __shfl_xor(acc[q], 32);
    }
}

// ---------------- Xe[e] = inv_e[e] * sum_{v in adj_e[e]} X[v] ----------------
__global__ __launch_bounds__(256) void edge_gather(
    const __half* __restrict__ Xh, const int* __restrict__ adj_e,
    const int* __restrict__ off_e, const float* __restrict__ inv_e,
    __half* __restrict__ Xeh)
{
    int wid  = blockIdx.x * 4 + (threadIdx.x >> 6);   // edge id (grid exact)
    int lane = threadIdx.x & 63;
    int beg = off_e[wid], end = off_e[wid + 1];
    float acc[8] = {0.f,0.f,0.f,0.f,0.f,0.f,0.f,0.f};
    for (int j = beg; j < end; j += 64) {
        int nj = end - j; if (nj > 64) nj = 64;
        int myidx = (lane < nj) ? adj_e[j + lane] : 0;
        process_chunk(Xh, myidx, nj, lane, acc);
    }
    reduce_groups(acc);
    if ((lane >> 3) == 0) {                            // lanes 0..7, c = lane
        float sc = inv_e[wid];
        union { uint4 u; __half2 h[4]; } O;
        O.h[0] = __floats2half2_rn(acc[0] * sc, acc[1] * sc);
        O.h[1] = __floats2half2_rn(acc[2] * sc, acc[3] * sc);
        O.h[2] = __floats2half2_rn(acc[4] * sc, acc[5] * sc);
        O.h[3] = __floats2half2_rn(acc[6] * sc, acc[7] * sc);
        ((uint4*)(Xeh + (size_t)wid * HID))[lane] = O.u;
    }
}

// ---------------- fused: node gather-mean-norm-mix -> LDS -> MFMA relu(Xi@W') ----------------
__global__ __launch_bounds__(256) void node_fused_mfma(
    const __half* __restrict__ Xeh, const int* __restrict__ adj_v,
    const int* __restrict__ off_v, const float* __restrict__ inv_v,
    const _Float16* __restrict__ X0h, const _Float16* __restrict__ Wp,
    _Float16* __restrict__ Xh)
{
    __shared__ _Float16 xi[16][72];          // pad row to 144 B: breaks bank conflicts
    int wv   = threadIdx.x >> 6;
    int lane = threadIdx.x & 63;
    int r16  = lane & 15;
    int kgrp = lane >> 4;
    int base = blockIdx.x * 16 + wv * 4;     // 4 nodes per wave, grid exact

    // B fragment: wave w owns n-tile n0 = w
    f16x8 bfA, bfB;
    #pragma unroll
    for (int j = 0; j < 8; ++j) {
        bfA[j] = Wp[(kgrp * 8 + j) * HID + wv * 16 + r16];
        bfB[j] = Wp[(32 + kgrp * 8 + j) * HID + wv * 16 + r16];
    }

    // hoisted offsets + first-chunk indices for 4 nodes (independent chains)
    int beg[4], deg[4], myidx[4];
    #pragma unroll
    for (int i = 0; i < 4; ++i) {
        beg[i] = off_v[base + i];
        deg[i] = off_v[base + i + 1] - beg[i];
    }
    #pragma unroll
    for (int i = 0; i < 4; ++i) {
        int nj = deg[i] < 64 ? deg[i] : 64;
        myidx[i] = (lane < nj) ? adj_v[beg[i] + lane] : 0;
    }

    #pragma unroll
    for (int i = 0; i < 4; ++i) {
        int row = base + i;
        float acc[8] = {0.f,0.f,0.f,0.f,0.f,0.f,0.f,0.f};
        int nj0 = deg[i] < 64 ? deg[i] : 64;
        process_chunk(Xeh, myidx[i], nj0, lane, acc);
        for (int j = beg[i] + 64; j < beg[i] + deg[i]; j += 64) {   // rare tail
            int nj = beg[i] + deg[i] - j; if (nj > 64) nj = 64;
            int mi = (lane < nj) ? adj_v[j + lane] : 0;
            process_chunk(Xeh, mi, nj, lane, acc);
        }
        reduce_groups(acc);
        float scm = inv_v[row];
        float m[8]; float s = 0.f;
        #pragma unroll
        for (int q = 0; q < 8; ++q) { m[q] = acc[q] * scm; s += m[q] * m[q]; }
        s += __shfl_xor(s, 1);
        s += __shfl_xor(s, 2);
        s += __shfl_xor(s, 4);
        float norm  = sqrtf(s);
        float scale = norm > 0.f ? 1.0f / norm : 0.f;
        if ((lane >> 3) == 0) {
            union { f16x8 v; uint4 u; } I;
            I.u = *(const uint4*)(X0h + (size_t)row * HID + lane * 8);
            union { f16x8 v; uint4 u; } O;
            #pragma unroll
            for (int q = 0; q < 8; ++q)
                O.v[q] = (_Float16)((1.0f - ALPHA) * (m[q] * scale) + ALPHA * (float)I.v[q]);
            *(uint4*)&xi[wv * 4 + i][lane * 8] = O.u;
        }
    }
    __syncthreads();

    // wave wv computes n-tile wv of relu(Xi[16x64] @ W')
    f16x8 a0 = *(const f16x8*)&xi[r16][kgrp * 8];
    f16x8 a1 = *(const f16x8*)&xi[r16][kgrp * 8 + 32];
    f32x4 acc = {0.f, 0.f, 0.f, 0.f};
    acc = __builtin_amdgcn_mfma_f32_16x16x32_f16(a0, bfA, acc, 0, 0, 0);
    acc = __builtin_amdgcn_mfma_f32_16x16x32_f16(a1, bfB, acc, 0, 0, 0);
    int rowbase = blockIdx.x * 16;
    #pragma unroll
    for (int r = 0; r < 4; ++r) {
        float y = acc[r] > 0.f ? acc[r] : 0.f;
        Xh[(size_t)(rowbase + kgrp * 4 + r) * HID + wv * 16 + r16] = (_Float16)y;
    }
}

// ---------------- out = Xh @ Wout + bout via MFMA (N=40 -> 3 n-tiles) ----------------
__global__ __launch_bounds__(256) void out_gemm(
    const _Float16* __restrict__ Xh, const float* __restrict__ Wout,
    const float* __restrict__ bout, float* __restrict__ out)
{
    int lane = threadIdx.x & 63;
    int wv   = threadIdx.x >> 6;
    int r16  = lane & 15;
    int kgrp = lane >> 4;
    f16x8 bf[3][2];
    float bias[3];
    #pragma unroll
    for (int n0 = 0; n0 < 3; ++n0) {
        int col = n0 * 16 + r16;
        bias[n0] = (col < NCLS) ? bout[col] : 0.f;
        #pragma unroll
        for (int kh = 0; kh < 2; ++kh)
            #pragma unroll
            for (int j = 0; j < 8; ++j) {
                int k = kh * 32 + kgrp * 8 + j;
                bf[n0][kh][j] = (col < NCLS) ? (_Float16)Wout[k * NCLS + col] : (_Float16)0.f;
            }
    }
    int nwaves = gridDim.x * 4;
    for (int t = blockIdx.x * 4 + wv; t < N_NODES / 16; t += nwaves) {
        int row0 = t * 16;
        const _Float16* ap = Xh + (size_t)(row0 + r16) * HID + kgrp * 8;
        f16x8 a0 = *(const f16x8*)(ap);
        f16x8 a1 = *(const f16x8*)(ap + 32);
        #pragma unroll
        for (int n0 = 0; n0 < 3; ++n0) {
            f32x4 acc = {0.f, 0.f, 0.f, 0.f};
            acc = __builtin_amdgcn_mfma_f32_16x16x32_f16(a0, bf[n0][0], acc, 0, 0, 0);
            acc = __builtin_amdgcn_mfma_f32_16x16x32_f16(a1, bf[n0][1], acc, 0, 0, 0);
            int col = n0 * 16 + r16;
            if (col < NCLS) {
                #pragma unroll
                for (int r = 0; r < 4; ++r)
                    out[(size_t)(row0 + kgrp * 4 + r) * NCLS + col] = acc[r] + bias[n0];
            }
        }
    }
}

extern "C" void kernel_launch(void* const* d_in, const int* in_sizes, int n_in,
                              void* d_out, int out_size, void* d_ws, size_t ws_size,
                              hipStream_t stream)
{
    const float* x      = (const float*)d_in[0];
    const int*   vertex = (const int*)  d_in[1];
    const int*   edges  = (const int*)  d_in[2];
    const float* W0     = (const float*)d_in[3];
    const float* b0     = (const float*)d_in[4];
    const float* Ws     = (const float*)d_in[5];
    const float* Wout   = (const float*)d_in[6];
    const float* bout   = (const float*)d_in[7];
    float* out = (float*)d_out;

    char* ws = (char*)d_ws;
    unsigned* binned_e = (unsigned*)ws; ws += (size_t)NNZ_C * 4;
    unsigned* binned_v = (unsigned*)ws; ws += (size_t)NNZ_C * 4;
    _Float16*  X0h  = (_Float16*)ws;  ws += (size_t)N_NODES * HID * 2;
    _Float16*  Xh   = (_Float16*)ws;  ws += (size_t)N_NODES * HID * 2;
    __half*    Xeh  = (__half*)ws;    ws += (size_t)N_EDGES * HID * 2;
    _Float16*  Wp   = (_Float16*)ws;  ws += (size_t)NLAYER * HID * HID * 2;
    int*   adj_e  = (int*)ws;     ws += (size_t)NNZ_C * 4;
    int*   adj_v  = (int*)ws;     ws += (size_t)NNZ_C * 4;
    int*   off_e  = (int*)ws;     ws += (size_t)(N_EDGES + 1) * 4;
    int*   off_v  = (int*)ws;     ws += (size_t)(N_NODES + 1) * 4;
    float* inv_e  = (float*)ws;   ws += (size_t)N_EDGES * 4;
    float* inv_v  = (float*)ws;   ws += (size_t)N_NODES * 4;
    int*   gcnt   = (int*)ws;     ws += (size_t)NB_TOT * 4;
    int*   boff_e = (int*)ws;     ws += (size_t)(NB_E + 1) * 4;
    int*   boff_v = (int*)ws;     ws += (size_t)(NB_V + 1) * 4;
    int*   curb   = (int*)ws;     ws += (size_t)NB_TOT * 4;

    const int p1_grid = (NNZ_C + 4095) / 4096;   // 245

    // ---- CSR build ----
    hipMemsetAsync(gcnt, 0, (size_t)NB_TOT * 4, stream);
    bucket_hist<<<p1_grid, 256, 0, stream>>>(vertex, edges, gcnt);
    bucket_scan<<<1, 1024, 0, stream>>>(gcnt, boff_e, boff_v, curb);
    bin_pass1_both<<<p1_grid, 256, 0, stream>>>(vertex, edges, curb, binned_e, binned_v);
    bin_pass2f<<<NB_E, 256, 0, stream>>>(binned_e, boff_e, ESHIFT, 16, N_EDGES, off_e, inv_e, adj_e);
    bin_pass2f<<<NB_V, 256, 0, stream>>>(binned_v, boff_v, VSHIFT, 15, N_NODES, off_v, inv_v, adj_v);

    float be0 = logf(0.5f / 1.f + 1.0f);
    float be1 = logf(0.5f / 2.f + 1.0f);
    float be2 = logf(0.5f / 3.f + 1.0f);
    float be3 = logf(0.5f / 4.f + 1.0f);
    make_wp<<<NLAYER, 256, 0, stream>>>(Ws, Wp, be0, be1, be2, be3);

    input_gemm<<<391, 256, 0, stream>>>(x, W0, b0, X0h);

    for (int l = 0; l < NLAYER; ++l) {
        const _Float16* Xin = (l == 0) ? X0h : Xh;
        edge_gather<<<N_EDGES / 4, 256, 0, stream>>>((const __half*)Xin, adj_e, off_e, inv_e, Xeh);
        node_fused_mfma<<<N_NODES / 16, 256, 0, stream>>>(
            Xeh, adj_v, off_v, inv_v, X0h, Wp + (size_t)l * HID * HID, Xh);
    }

    out_gemm<<<391, 256, 0, stream>>>(Xh, Wout, bout, out);
}

// Round 11
// 281.529 us; speedup vs baseline: 1.0778x; 1.0778x over previous
//
#include <hip/hip_runtime.h>
#include <hip/hip_fp16.h>
#include <math.h>

#define N_NODES 50000
#define N_EDGES 20000
#define NNZ_C   1000000
#define F_IN    128
#define HID     64
#define NCLS    40
#define NLAYER  4
#define ALPHA   0.1f

#define ESHIFT  6                        // 64 edges / bucket
#define VSHIFT  7                        // 128 vertices / bucket
#define NB_E    ((N_EDGES + 63) / 64)    // 313
#define NB_V    ((N_NODES + 127) / 128)  // 391
#define NB_TOT  (NB_E + NB_V)            // 704

typedef _Float16 f16x8 __attribute__((ext_vector_type(8)));
typedef float    f32x4 __attribute__((ext_vector_type(4)));

// ---------------- X0h = relu(x @ W0 + b0) via MFMA, fp16 out ----------------
__global__ __launch_bounds__(256) void input_gemm(
    const float* __restrict__ x, const float* __restrict__ W0,
    const float* __restrict__ b0, _Float16* __restrict__ X0h)
{
    int lane = threadIdx.x & 63;
    int wv   = threadIdx.x >> 6;
    int r16  = lane & 15;
    int kgrp = lane >> 4;                    // 0..3
    f16x8 bf[4][4];
    #pragma unroll
    for (int n0 = 0; n0 < 4; ++n0)
        #pragma unroll
        for (int kh = 0; kh < 4; ++kh)
            #pragma unroll
            for (int j = 0; j < 8; ++j)
                bf[n0][kh][j] = (_Float16)W0[(kh * 32 + kgrp * 8 + j) * HID + n0 * 16 + r16];
    float bias[4];
    #pragma unroll
    for (int n0 = 0; n0 < 4; ++n0) bias[n0] = b0[n0 * 16 + r16];

    int nwaves = gridDim.x * 4;
    for (int t = blockIdx.x * 4 + wv; t < N_NODES / 16; t += nwaves) {
        int row0 = t * 16;
        const float* xp = x + (size_t)(row0 + r16) * F_IN + kgrp * 8;
        f16x8 a[4];
        #pragma unroll
        for (int kh = 0; kh < 4; ++kh) {
            float4 u0 = *(const float4*)(xp + kh * 32);
            float4 u1 = *(const float4*)(xp + kh * 32 + 4);
            a[kh][0] = (_Float16)u0.x; a[kh][1] = (_Float16)u0.y;
            a[kh][2] = (_Float16)u0.z; a[kh][3] = (_Float16)u0.w;
            a[kh][4] = (_Float16)u1.x; a[kh][5] = (_Float16)u1.y;
            a[kh][6] = (_Float16)u1.z; a[kh][7] = (_Float16)u1.w;
        }
        #pragma unroll
        for (int n0 = 0; n0 < 4; ++n0) {
            f32x4 acc = {0.f, 0.f, 0.f, 0.f};
            #pragma unroll
            for (int kh = 0; kh < 4; ++kh)
                acc = __builtin_amdgcn_mfma_f32_16x16x32_f16(a[kh], bf[n0][kh], acc, 0, 0, 0);
            #pragma unroll
            for (int r = 0; r < 4; ++r) {
                float y = acc[r] + bias[n0];
                y = y > 0.f ? y : 0.f;
                X0h[(size_t)(row0 + kgrp * 4 + r) * HID + n0 * 16 + r16] = (_Float16)y;
            }
        }
    }
}

// ---------------- W'[l] = (1-beta_l) I + beta_l Ws[l], fp16 ----------------
__global__ __launch_bounds__(256) void make_wp(
    const float* __restrict__ Ws, _Float16* __restrict__ Wp,
    float be0, float be1, float be2, float be3)
{
    int l = blockIdx.x;
    float beta = (l == 0) ? be0 : (l == 1) ? be1 : (l == 2) ? be2 : be3;
    for (int i = threadIdx.x; i < HID * HID; i += 256) {
        int k = i >> 6, n = i & 63;
        float v = beta * Ws[l * HID * HID + i] + ((k == n) ? (1.f - beta) : 0.f);
        Wp[l * HID * HID + i] = (_Float16)v;
    }
}

// ---------------- per-block LDS bucket histogram (704 coarse buckets) ----------------
__global__ __launch_bounds__(256) void bucket_hist(
    const int* __restrict__ vertex, const int* __restrict__ edges,
    int* __restrict__ gcnt)
{
    __shared__ int h[NB_TOT];
    int tid = threadIdx.x;
    for (int i = tid; i < NB_TOT; i += 256) h[i] = 0;
    __syncthreads();
    int base = blockIdx.x * 4096;
    int n = NNZ_C - base; if (n > 4096) n = 4096;   // always multiple of 4
    for (int i = tid * 4; i < n; i += 1024) {
        int4 e4 = *(const int4*)(edges  + base + i);
        int4 v4 = *(const int4*)(vertex + base + i);
        atomicAdd(&h[e4.x >> ESHIFT], 1);
        atomicAdd(&h[e4.y >> ESHIFT], 1);
        atomicAdd(&h[e4.z >> ESHIFT], 1);
        atomicAdd(&h[e4.w >> ESHIFT], 1);
        atomicAdd(&h[NB_E + (v4.x >> VSHIFT)], 1);
        atomicAdd(&h[NB_E + (v4.y >> VSHIFT)], 1);
        atomicAdd(&h[NB_E + (v4.z >> VSHIFT)], 1);
        atomicAdd(&h[NB_E + (v4.w >> VSHIFT)], 1);
    }
    __syncthreads();
    for (int i = tid; i < NB_TOT; i += 256)
        if (h[i]) atomicAdd(&gcnt[i], h[i]);
}

// ---------------- scan 704 bucket counts -> bucket offsets + cursors ----------------
__global__ __launch_bounds__(1024) void bucket_scan(
    const int* __restrict__ gcnt, int* __restrict__ boff_e,
    int* __restrict__ boff_v, int* __restrict__ curb)
{
    __shared__ int tmp[1024];
    int tid = threadIdx.x;
    int v = (tid < NB_TOT) ? gcnt[tid] : 0;
    tmp[tid] = v;
    __syncthreads();
    for (int d = 1; d < 1024; d <<= 1) {
        int t = (tid >= d) ? tmp[tid - d] : 0;
        __syncthreads();
        tmp[tid] += t;
        __syncthreads();
    }
    if (tid < NB_TOT) {
        int excl = tmp[tid] - v;
        int off = (tid < NB_E) ? excl : excl - NNZ_C;  // v-part 0-based
        if (tid < NB_E) boff_e[tid] = off; else boff_v[tid - NB_E] = off;
        curb[tid] = off;
    }
    if (tid == 0) { boff_e[NB_E] = NNZ_C; boff_v[NB_V] = NNZ_C; }
}

// ---------------- pass 1 (both sides): bin packed 32-bit pairs, single read ----------------
__global__ __launch_bounds__(256) void bin_pass1_both(
    const int* __restrict__ vertex, const int* __restrict__ edges,
    int* __restrict__ curb,
    unsigned* __restrict__ binned_e,
    unsigned* __restrict__ binned_v)
{
    __shared__ int hist[NB_TOT];
    __shared__ int base[NB_TOT];
    int tid = threadIdx.x;
    int blk = blockIdx.x * 4096;
    int nh = NNZ_C - blk; if (nh > 4096) nh = 4096;   // multiple of 4
    // register-cache this block's pairs: 4 chunks x int4 per thread
    int ee[16], vv[16];
    int nche = 0;
    #pragma unroll
    for (int k = 0; k < 4; ++k) {
        int i = tid * 4 + k * 1024;
        if (i < nh) {
            int4 e4 = *(const int4*)(edges  + blk + i);
            int4 v4 = *(const int4*)(vertex + blk + i);
            ee[k*4+0]=e4.x; ee[k*4+1]=e4.y; ee[k*4+2]=e4.z; ee[k*4+3]=e4.w;
            vv[k*4+0]=v4.x; vv[k*4+1]=v4.y; vv[k*4+2]=v4.z; vv[k*4+3]=v4.w;
            nche = k + 1;
        }
    }
    for (int i = tid; i < NB_TOT; i += 256) hist[i] = 0;
    __syncthreads();
    for (int k = 0; k < nche; ++k) {
        #pragma unroll
        for (int q = 0; q < 4; ++q) {
            atomicAdd(&hist[ee[k*4+q] >> ESHIFT], 1);
            atomicAdd(&hist[NB_E + (vv[k*4+q] >> VSHIFT)], 1);
        }
    }
    __syncthreads();
    for (int i = tid; i < NB_TOT; i += 256) {
        int c = hist[i];
        base[i] = c ? atomicAdd(&curb[i], c) : 0;
        hist[i] = 0;
    }
    __syncthreads();
    for (int k = 0; k < nche; ++k) {
        #pragma unroll
        for (int q = 0; q < 4; ++q) {
            int e = ee[k*4+q], v = vv[k*4+q];
            int be = e >> ESHIFT;
            int r  = atomicAdd(&hist[be], 1);
            binned_e[base[be] + r] = ((unsigned)e << 16) | (unsigned)v;   // e<2^15, v<2^16
            int bv = NB_E + (v >> VSHIFT);
            int r2 = atomicAdd(&hist[bv], 1);
            binned_v[base[bv] + r2] = ((unsigned)v << 15) | (unsigned)e;  // e<2^15
        }
    }
}

// ---------------- pass 2: per bucket -> local count/scan, write off/inv, place adj ----------------
__global__ __launch_bounds__(256) void bin_pass2f(
    const unsigned* __restrict__ binned, const int* __restrict__ boff,
    int shift, int kshift, int nkeys,
    int* __restrict__ off, float* __restrict__ inv, int* __restrict__ adj)
{
    __shared__ int lcnt[128];
    __shared__ int ts[128];
    __shared__ int lcur[128];
    int b  = blockIdx.x;
    int k0 = b << shift;
    int bs = 1 << shift;
    int kn = nkeys - k0; if (kn > bs) kn = bs;
    int tid = threadIdx.x;
    unsigned vmask = (1u << kshift) - 1u;
    if (tid < 128) lcnt[tid] = 0;
    __syncthreads();
    int beg = boff[b], end = boff[b + 1];
    for (int j = beg + tid; j < end; j += 256)
        atomicAdd(&lcnt[(int)(binned[j] >> kshift) - k0], 1);
    __syncthreads();
    int c = 0;
    if (tid < 128) { c = lcnt[tid]; ts[tid] = c; }
    __syncthreads();
    #pragma unroll
    for (int d = 1; d < 128; d <<= 1) {
        int t = 0;
        if (tid < 128 && tid >= d) t = ts[tid - d];
        __syncthreads();
        if (tid < 128) ts[tid] += t;
        __syncthreads();
    }
    if (tid < kn) {
        int pos = beg + ts[tid] - c;
        off[k0 + tid] = pos;
        inv[k0 + tid] = 1.0f / fmaxf((float)c, 1.0f);
        lcur[tid] = pos;
    }
    if (b == 0 && tid == 0) off[nkeys] = NNZ_C;
    __syncthreads();
    for (int j = beg + tid; j < end; j += 256) {
        unsigned p = binned[j];
        int k = (int)(p >> kshift) - k0;
        int v = (int)(p & vmask);
        adj[atomicAdd(&lcur[k], 1)] = v;
    }
}

// ---- gather core: wave = 1 segment; 8 groups x 8 rows in flight;
//      index shfls hoisted, 8 predicated loads issued together.
__device__ __forceinline__ void gather_rows(
    const __half* __restrict__ src, const int* __restrict__ adj,
    int beg, int end, int lane, float acc[8])
{
    int g = lane >> 3, c = lane & 7;
    for (int j = beg; j < end; j += 64) {
        int nj = end - j; if (nj > 64) nj = 64;
        int myidx = (lane < nj) ? adj[j + lane] : 0;     // coalesced index load
        int idx[8];
        #pragma unroll
        for (int s = 0; s < 8; ++s)
            idx[s] = __shfl(myidx, ((s << 3) + g) & 63); // hoisted broadcasts
        #pragma unroll
        for (int s = 0; s < 8; ++s) {
            int r = (s << 3) + g;
            if (r < nj) {
                uint4 raw = ((const uint4*)(src + (size_t)idx[s] * HID))[c];
                union { uint4 u; __half2 h[4]; } U; U.u = raw;
                float2 f0 = __half22float2(U.h[0]);
                float2 f1 = __half22float2(U.h[1]);
                float2 f2 = __half22float2(U.h[2]);
                float2 f3 = __half22float2(U.h[3]);
                acc[0] += f0.x; acc[1] += f0.y;
                acc[2] += f1.x; acc[3] += f1.y;
                acc[4] += f2.x; acc[5] += f2.y;
                acc[6] += f3.x; acc[7] += f3.y;
            }
        }
    }
    #pragma unroll
    for (int q = 0; q < 8; ++q) {
        acc[q] += __shfl_xor(acc[q], 8);
        acc[q] += __shfl_xor(acc[q], 16);
        acc[q] += __shfl_xor(acc[q], 32);
    }
}

// ---------------- Xe[e] = inv_e[e] * sum_{v in adj_e[e]} X[v] ----------------
__global__ __launch_bounds__(256) void edge_gather(
    const __half* __restrict__ Xh, const int* __restrict__ adj_e,
    const int* __restrict__ off_e, const float* __restrict__ inv_e,
    __half* __restrict__ Xeh)
{
    int wid  = blockIdx.x * 4 + (threadIdx.x >> 6);   // edge id (grid exact)
    int lane = threadIdx.x & 63;
    float acc[8] = {0.f,0.f,0.f,0.f,0.f,0.f,0.f,0.f};
    gather_rows(Xh, adj_e, off_e[wid], off_e[wid + 1], lane, acc);
    if ((lane >> 3) == 0) {                            // lanes 0..7, c = lane
        float sc = inv_e[wid];
        union { uint4 u; __half2 h[4]; } O;
        O.h[0] = __floats2half2_rn(acc[0] * sc, acc[1] * sc);
        O.h[1] = __floats2half2_rn(acc[2] * sc, acc[3] * sc);
        O.h[2] = __floats2half2_rn(acc[4] * sc, acc[5] * sc);
        O.h[3] = __floats2half2_rn(acc[6] * sc, acc[7] * sc);
        ((uint4*)(Xeh + (size_t)wid * HID))[lane] = O.u;
    }
}

// ---------------- node gather: mean -> l2norm -> alpha-mix -> Xi fp16 ----------------
__global__ __launch_bounds__(256) void node_gather(
    const __half* __restrict__ Xeh, const int* __restrict__ adj_v,
    const int* __restrict__ off_v, const float* __restrict__ inv_v,
    const _Float16* __restrict__ X0h, _Float16* __restrict__ Xi)
{
    int wv   = threadIdx.x >> 6;
    int row  = blockIdx.x * 4 + wv;          // grid exact: always < N_NODES
    int lane = threadIdx.x & 63;
    float acc[8] = {0.f,0.f,0.f,0.f,0.f,0.f,0.f,0.f};
    gather_rows(Xeh, adj_v, off_v[row], off_v[row + 1], lane, acc);
    float scm = inv_v[row];
    float m[8]; float s = 0.f;
    #pragma unroll
    for (int q = 0; q < 8; ++q) { m[q] = acc[q] * scm; s += m[q] * m[q]; }
    s += __shfl_xor(s, 1);
    s += __shfl_xor(s, 2);
    s += __shfl_xor(s, 4);                    // full row sum-of-squares
    float norm  = sqrtf(s);
    float scale = norm > 0.f ? 1.0f / norm : 0.f;
    if ((lane >> 3) == 0) {                   // lanes 0..7, c = lane
        union { f16x8 v; uint4 u; } I;
        I.u = *(const uint4*)(X0h + (size_t)row * HID + lane * 8);
        union { f16x8 v; uint4 u; } O;
        #pragma unroll
        for (int q = 0; q < 8; ++q)
            O.v[q] = (_Float16)((1.0f - ALPHA) * (m[q] * scale) + ALPHA * (float)I.v[q]);
        *(uint4*)(Xi + (size_t)row * HID + lane * 8) = O.u;
    }
}

// ---------------- X = relu(Xi @ W') via MFMA 16x16x32 f16 ----------------
__global__ __launch_bounds__(256) void layer_gemm(
    const _Float16* __restrict__ Xi, const _Float16* __restrict__ Wp,
    _Float16* __restrict__ Xh)
{
    int lane = threadIdx.x & 63;
    int wv   = threadIdx.x >> 6;
    int r16  = lane & 15;
    int kgrp = lane >> 4;
    f16x8 bf[4][2];
    #pragma unroll
    for (int n0 = 0; n0 < 4; ++n0)
        #pragma unroll
        for (int kh = 0; kh < 2; ++kh) {
            #pragma unroll
            for (int j = 0; j < 8; ++j)
                bf[n0][kh][j] = Wp[(kh * 32 + kgrp * 8 + j) * HID + n0 * 16 + r16];
        }
    int nwaves = gridDim.x * 4;
    for (int t = blockIdx.x * 4 + wv; t < N_NODES / 16; t += nwaves) {
        int row0 = t * 16;
        const _Float16* ap = Xi + (size_t)(row0 + r16) * HID + kgrp * 8;
        f16x8 a0 = *(const f16x8*)(ap);
        f16x8 a1 = *(const f16x8*)(ap + 32);
        #pragma unroll
        for (int n0 = 0; n0 < 4; ++n0) {
            f32x4 acc = {0.f, 0.f, 0.f, 0.f};
            acc = __builtin_amdgcn_mfma_f32_16x16x32_f16(a0, bf[n0][0], acc, 0, 0, 0);
            acc = __builtin_amdgcn_mfma_f32_16x16x32_f16(a1, bf[n0][1], acc, 0, 0, 0);
            #pragma unroll
            for (int r = 0; r < 4; ++r) {
                float y = acc[r] > 0.f ? acc[r] : 0.f;
                Xh[(size_t)(row0 + kgrp * 4 + r) * HID + n0 * 16 + r16] = (_Float16)y;
            }
        }
    }
}

// ---------------- out = Xh @ Wout + bout via MFMA (N=40 -> 3 n-tiles) ----------------
__global__ __launch_bounds__(256) void out_gemm(
    const _Float16* __restrict__ Xh, const float* __restrict__ Wout,
    const float* __restrict__ bout, float* __restrict__ out)
{
    int lane = threadIdx.x & 63;
    int wv   = threadIdx.x >> 6;
    int r16  = lane & 15;
    int kgrp = lane >> 4;
    f16x8 bf[3][2];
    float bias[3];
    #pragma unroll
    for (int n0 = 0; n0 < 3; ++n0) {
        int col = n0 * 16 + r16;
        bias[n0] = (col < NCLS) ? bout[col] : 0.f;
        #pragma unroll
        for (int kh = 0; kh < 2; ++kh)
            #pragma unroll
            for (int j = 0; j < 8; ++j) {
                int k = kh * 32 + kgrp * 8 + j;
                bf[n0][kh][j] = (col < NCLS) ? (_Float16)Wout[k * NCLS + col] : (_Float16)0.f;
            }
    }
    int nwaves = gridDim.x * 4;
    for (int t = blockIdx.x * 4 + wv; t < N_NODES / 16; t += nwaves) {
        int row0 = t * 16;
        const _Float16* ap = Xh + (size_t)(row0 + r16) * HID + kgrp * 8;
        f16x8 a0 = *(const f16x8*)(ap);
        f16x8 a1 = *(const f16x8*)(ap + 32);
        #pragma unroll
        for (int n0 = 0; n0 < 3; ++n0) {
            f32x4 acc = {0.f, 0.f, 0.f, 0.f};
            acc = __builtin_amdgcn_mfma_f32_16x16x32_f16(a0, bf[n0][0], acc, 0, 0, 0);
            acc = __builtin_amdgcn_mfma_f32_16x16x32_f16(a1, bf[n0][1], acc, 0, 0, 0);
            int col = n0 * 16 + r16;
            if (col < NCLS) {
                #pragma unroll
                for (int r = 0; r < 4; ++r)
                    out[(size_t)(row0 + kgrp * 4 + r) * NCLS + col] = acc[r] + bias[n0];
            }
        }
    }
}

extern "C" void kernel_launch(void* const* d_in, const int* in_sizes, int n_in,
                              void* d_out, int out_size, void* d_ws, size_t ws_size,
                              hipStream_t stream)
{
    const float* x      = (const float*)d_in[0];
    const int*   vertex = (const int*)  d_in[1];
    const int*   edges  = (const int*)  d_in[2];
    const float* W0     = (const float*)d_in[3];
    const float* b0     = (const float*)d_in[4];
    const float* Ws     = (const float*)d_in[5];
    const float* Wout   = (const float*)d_in[6];
    const float* bout   = (const float*)d_in[7];
    float* out = (float*)d_out;

    char* ws = (char*)d_ws;
    unsigned* binned_e = (unsigned*)ws; ws += (size_t)NNZ_C * 4;
    unsigned* binned_v = (unsigned*)ws; ws += (size_t)NNZ_C * 4;
    _Float16*  X0h  = (_Float16*)ws;  ws += (size_t)N_NODES * HID * 2;
    _Float16*  Xh   = (_Float16*)ws;  ws += (size_t)N_NODES * HID * 2;
    _Float16*  Xi   = (_Float16*)ws;  ws += (size_t)N_NODES * HID * 2;
    __half*    Xeh  = (__half*)ws;    ws += (size_t)N_EDGES * HID * 2;
    _Float16*  Wp   = (_Float16*)ws;  ws += (size_t)NLAYER * HID * HID * 2;
    int*   adj_e  = (int*)ws;     ws += (size_t)NNZ_C * 4;
    int*   adj_v  = (int*)ws;     ws += (size_t)NNZ_C * 4;
    int*   off_e  = (int*)ws;     ws += (size_t)(N_EDGES + 1) * 4;
    int*   off_v  = (int*)ws;     ws += (size_t)(N_NODES + 1) * 4;
    float* inv_e  = (float*)ws;   ws += (size_t)N_EDGES * 4;
    float* inv_v  = (float*)ws;   ws += (size_t)N_NODES * 4;
    int*   gcnt   = (int*)ws;     ws += (size_t)NB_TOT * 4;
    int*   boff_e = (int*)ws;     ws += (size_t)(NB_E + 1) * 4;
    int*   boff_v = (int*)ws;     ws += (size_t)(NB_V + 1) * 4;
    int*   curb   = (int*)ws;     ws += (size_t)NB_TOT * 4;

    const int p1_grid = (NNZ_C + 4095) / 4096;   // 245

    // ---- CSR build ----
    hipMemsetAsync(gcnt, 0, (size_t)NB_TOT * 4, stream);
    bucket_hist<<<p1_grid, 256, 0, stream>>>(vertex, edges, gcnt);
    bucket_scan<<<1, 1024, 0, stream>>>(gcnt, boff_e, boff_v, curb);
    bin_pass1_both<<<p1_grid, 256, 0, stream>>>(vertex, edges, curb, binned_e, binned_v);
    bin_pass2f<<<NB_E, 256, 0, stream>>>(binned_e, boff_e, ESHIFT, 16, N_EDGES, off_e, inv_e, adj_e);
    bin_pass2f<<<NB_V, 256, 0, stream>>>(binned_v, boff_v, VSHIFT, 15, N_NODES, off_v, inv_v, adj_v);

    float be0 = logf(0.5f / 1.f + 1.0f);
    float be1 = logf(0.5f / 2.f + 1.0f);
    float be2 = logf(0.5f / 3.f + 1.0f);
    float be3 = logf(0.5f / 4.f + 1.0f);
    make_wp<<<NLAYER, 256, 0, stream>>>(Ws, Wp, be0, be1, be2, be3);

    input_gemm<<<391, 256, 0, stream>>>(x, W0, b0, X0h);

    for (int l = 0; l < NLAYER; ++l) {
        const _Float16* Xin = (l == 0) ? X0h : Xh;
        edge_gather<<<N_EDGES / 4, 256, 0, stream>>>((const __half*)Xin, adj_e, off_e, inv_e, Xeh);
        node_gather<<<N_NODES / 4, 256, 0, stream>>>(
            Xeh, adj_v, off_v, inv_v, X0h, Xi);
        layer_gemm<<<391, 256, 0, stream>>>(Xi, Wp + (size_t)l * HID * HID, Xh);
    }

    out_gemm<<<391, 256, 0, stream>>>(Xh, Wout, bout, out);
}